// Round 2
// baseline (192.934 us; speedup 1.0000x reference)
//
#include <hip/hip_runtime.h>
#include <math.h>

#define Bb 8
#define Cc 64
#define Nn 256
#define FD 128
#define TILE (Nn * FD)       // 32768 floats per (b,c)
#define GRID 512             // one block per (b,c) tile
#define SPIN_MAX 200000      // bounded spin: fail loudly, never hang

typedef float floatx4 __attribute__((ext_vector_type(4)));

// ---------------------------------------------------------------------------
// Fused single kernel. 512 blocks x 256 threads, __launch_bounds__(256,2):
// co-residency needs only 2 blocks/CU (guaranteed for any VGPR <= 256),
// so the arrival-counter grid barrier is safe. Bounded spin as safety net.
//
// Phase 1: each block owns one full (b,c) tile (256 rows, 128 KB).
//   4 chunks x 64 rows; per chunk the mask logit dh is half-wave-reduced and
//   broadcast via LDS; dotS/dotQ/rowsum/rowsumsq stay as per-lane register
//   partials and are mask-folded after the broadcast. Block-wide reduce at
//   the end -> 6 masked partials + 2 source dots, atomicAdd into zeroed
//   bpart[bc*8..+7] (device-scope => cross-XCD visible). Masks stay in LDS.
// Barrier: device-scope arrival counter (memset to 0 each launch).
// Phase 2: read the 64-float partial table for channel c (8 batches x 8),
//   finalize softmax weights + BN scale/shift redundantly (uniform, cheap),
//   then elu(fma(h, w*scale, shift)) over the block's own L2/L3-warm 128 KB
//   slice, nontemporal stores.
// ---------------------------------------------------------------------------
__global__ __launch_bounds__(256, 2) void fused(
    const float* __restrict__ h, const float* __restrict__ op,
    const float* __restrict__ opS, const float* __restrict__ opQ,
    const float* __restrict__ gamma, const float* __restrict__ beta,
    float* __restrict__ out, float* __restrict__ bpart,
    unsigned int* __restrict__ counter) {
  const int bc = blockIdx.x;
  const int c = bc & (Cc - 1), b = bc >> 6;
  const float* __restrict__ tile = h + (size_t)bc * TILE;
  const int tid = threadIdx.x, lane = tid & 63, wv = tid >> 6;
  const int hw = tid >> 5, hl = tid & 31;

  __shared__ float s_dh[64];
  __shared__ unsigned long long s_mask[4];
  __shared__ float s_red[4][6];
  __shared__ float s_csq[3];   // cs (mask bias), ss, qq (source-row dots)
  __shared__ float s_part[64]; // 8 batches x 8 partials for channel c
  __shared__ float s_a[256];   // per-row weight*scale

  // wave 0: source-row dots
  if (wv == 0) {
    const float* __restrict__ opc  = op  + c * 2 * FD;
    const float* __restrict__ opSc = opS + c * 2 * FD;
    const float* __restrict__ opQc = opQ + c * 2 * FD;
    const float a0 = tile[lane], a1 = tile[lane + 64];
    float cs  = a0 * opc[lane]       + a1 * opc[lane + 64];
    float ssv = a0 * opSc[FD + lane] + a1 * opSc[FD + lane + 64];
    float qqv = a0 * opQc[FD + lane] + a1 * opQc[FD + lane + 64];
#pragma unroll
    for (int off = 32; off >= 1; off >>= 1) {
      cs  += __shfl_xor(cs,  off, 64);
      ssv += __shfl_xor(ssv, off, 64);
      qqv += __shfl_xor(qqv, off, 64);
    }
    if (lane == 0) { s_csq[0] = cs; s_csq[1] = ssv; s_csq[2] = qqv; }
  }

  const float4 oH = ((const float4*)(op  + c * 2 * FD + FD))[hl];
  const float4 oS = ((const float4*)(opS + c * 2 * FD))[hl];
  const float4 oQ = ((const float4*)(opQ + c * 2 * FD))[hl];

  float a_ds = 0, a_dq = 0, a_rsm = 0, a_rsq = 0, a_rssm = 0, a_rssq = 0;

#pragma unroll
  for (int chunk = 0; chunk < 4; ++chunk) {
    const int rowbase = chunk * 64;
    float dsp[8], dqp[8], rsp[8], rssp[8];
    // 8 half-waves x 8 rows = 64 rows; one float4 per half-wave-lane per row.
#pragma unroll
    for (int i = 0; i < 8; ++i) {
      const int nl = hw * 8 + i;
      const float4 v = ((const float4*)(tile + (size_t)(rowbase + nl) * FD))[hl];
      float dh = v.x * oH.x + v.y * oH.y + v.z * oH.z + v.w * oH.w;
      dsp[i]  = v.x * oS.x + v.y * oS.y + v.z * oS.z + v.w * oS.w;
      dqp[i]  = v.x * oQ.x + v.y * oQ.y + v.z * oQ.z + v.w * oQ.w;
      rsp[i]  = v.x + v.y + v.z + v.w;
      rssp[i] = v.x * v.x + v.y * v.y + v.z * v.z + v.w * v.w;
#pragma unroll
      for (int off = 16; off >= 1; off >>= 1) dh += __shfl_xor(dh, off, 64);
      if (hl == 0) s_dh[nl] = dh;
    }
    __syncthreads();
    const float cs = s_csq[0];
    if (wv == 0) {
      const bool m = (s_dh[lane] + cs) >= 0.0f;
      const unsigned long long bits = __ballot(m);
      if (lane == 0) s_mask[chunk] = bits;
    }
#pragma unroll
    for (int i = 0; i < 8; ++i) {
      const bool m = (s_dh[hw * 8 + i] + cs) >= 0.0f;
      a_ds   += m ? dsp[i]  : 0.0f;
      a_dq   += m ? 0.0f    : dqp[i];
      a_rsm  += m ? rsp[i]  : 0.0f;
      a_rsq  += m ? 0.0f    : rsp[i];
      a_rssm += m ? rssp[i] : 0.0f;
      a_rssq += m ? 0.0f    : rssp[i];
    }
    __syncthreads();  // protect s_dh reuse by next chunk
  }

  // block-wide reduction of the 6 masked partials
#pragma unroll
  for (int off = 32; off >= 1; off >>= 1) {
    a_ds   += __shfl_xor(a_ds,   off, 64);
    a_dq   += __shfl_xor(a_dq,   off, 64);
    a_rsm  += __shfl_xor(a_rsm,  off, 64);
    a_rsq  += __shfl_xor(a_rsq,  off, 64);
    a_rssm += __shfl_xor(a_rssm, off, 64);
    a_rssq += __shfl_xor(a_rssq, off, 64);
  }
  if (lane == 0) {
    s_red[wv][0] = a_ds;  s_red[wv][1] = a_dq;
    s_red[wv][2] = a_rsm; s_red[wv][3] = a_rsq;
    s_red[wv][4] = a_rssm; s_red[wv][5] = a_rssq;
  }
  __syncthreads();
  if (tid < 6) {
    atomicAdd(&bpart[bc * 8 + tid],
              s_red[0][tid] + s_red[1][tid] + s_red[2][tid] + s_red[3][tid]);
  }
  if (tid == 6) atomicAdd(&bpart[bc * 8 + 6], s_csq[1]);
  if (tid == 7) atomicAdd(&bpart[bc * 8 + 7], s_csq[2]);

  // ---- global barrier: syncthreads drains the atomics, then one arrival
  // increment per block, bounded spin (fail loudly, never hang). ----
  __syncthreads();
  if (tid == 0) {
    __hip_atomic_fetch_add(counter, 1u, __ATOMIC_ACQ_REL,
                           __HIP_MEMORY_SCOPE_AGENT);
    int it = 0;
    while (__hip_atomic_load(counter, __ATOMIC_ACQUIRE,
                             __HIP_MEMORY_SCOPE_AGENT) < (unsigned)GRID) {
      if (++it > SPIN_MAX) break;  // co-residency failed: fail test, no hang
      __builtin_amdgcn_s_sleep(4);
    }
  }
  __syncthreads();

  // ---- phase 2: finalize (uniform per block) ----
  if (tid < 64) {
    s_part[tid] = __hip_atomic_load(
        &bpart[(size_t)(((tid >> 3) * Cc + c) * 8 + (tid & 7))],
        __ATOMIC_ACQUIRE, __HIP_MEMORY_SCOPE_AGENT);
  }
  __syncthreads();

  float S = 0.0f, SS = 0.0f, w_s = 0.0f, w_q = 0.0f;
#pragma unroll
  for (int bb = 0; bb < Bb; ++bb) {
    const float* p = &s_part[bb * 8];
    const float sa = p[0] * (1.0f / Nn) + p[6];
    const float qa = p[1] * (1.0f / Nn) + p[7];
    const float mx = fmaxf(sa, qa);
    const float es = __expf(sa - mx), eq = __expf(qa - mx);
    const float inv = 1.0f / (es + eq);
    const float ws = es * inv, wq = eq * inv;
    S  += ws * p[2] + wq * p[3];
    SS += ws * ws * p[4] + wq * wq * p[5];
    if (bb == b) { w_s = ws; w_q = wq; }
  }
  const float invcnt = 1.0f / (float)(Bb * Nn * FD);
  const float mean = S * invcnt;
  const float var  = SS * invcnt - mean * mean;
  const float scale = gamma[c] * rsqrtf(var + 1e-5f);
  const float shift = beta[c] - mean * scale;

  {
    const unsigned long long mw = s_mask[tid >> 6];   // row = tid (0..255)
    const float w = ((mw >> (tid & 63)) & 1ull) ? w_s : w_q;
    s_a[tid] = w * scale;
  }
  __syncthreads();

  // ---- phase 2: elementwise over the block's own (cache-warm) 128 KB slice
  const float4* __restrict__ h4 = (const float4*)tile;
  floatx4* __restrict__ o4 = (floatx4*)(out + (size_t)bc * TILE);
#pragma unroll 8
  for (int k = 0; k < 32; ++k) {
    const int idx = k * 256 + tid;
    const float a = s_a[idx >> 5];   // 32 float4 per row -> broadcast per 32 lanes
    const float4 v = h4[idx];
    floatx4 r;
    r.x = fmaf(v.x, a, shift);
    r.y = fmaf(v.y, a, shift);
    r.z = fmaf(v.z, a, shift);
    r.w = fmaf(v.w, a, shift);
    r.x = r.x > 0.0f ? r.x : __expf(r.x) - 1.0f;
    r.y = r.y > 0.0f ? r.y : __expf(r.y) - 1.0f;
    r.z = r.z > 0.0f ? r.z : __expf(r.z) - 1.0f;
    r.w = r.w > 0.0f ? r.w : __expf(r.w) - 1.0f;
    __builtin_nontemporal_store(r, &o4[idx]);
  }
}

extern "C" void kernel_launch(void* const* d_in, const int* in_sizes, int n_in,
                              void* d_out, int out_size, void* d_ws, size_t ws_size,
                              hipStream_t stream) {
  const float* h     = (const float*)d_in[0];
  const float* op    = (const float*)d_in[1];
  const float* opS   = (const float*)d_in[2];
  const float* opQ   = (const float*)d_in[3];
  const float* gamma = (const float*)d_in[4];
  const float* beta  = (const float*)d_in[5];
  float* out = (float*)d_out;

  float* bpart = (float*)d_ws;                               // 512*8*4 = 16 KB
  unsigned int* counter = (unsigned int*)((char*)d_ws + 16384);

  // zero the atomic accumulators + barrier counter (stream op, capturable)
  hipMemsetAsync(d_ws, 0, 16384 + 64, stream);
  fused<<<GRID, 256, 0, stream>>>(h, op, opS, opQ, gamma, beta, out,
                                  bpart, counter);
}

// Round 3
// 132.607 us; speedup vs baseline: 1.4549x; 1.4549x over previous
//
#include <hip/hip_runtime.h>
#include <math.h>

#define Bb 8
#define Cc 64
#define Nn 256
#define FD 128
#define SEGS 4
#define ROWS 64          // rows per block
#define TILE (Nn * FD)   // 32768 floats per (b,c)

typedef float floatx4 __attribute__((ext_vector_type(4)));

// ---------------------------------------------------------------------------
// s1: one block per (bc, seg) — 64 rows, single pass over its 32 KB slice.
// Only the mask logit dh is reduced per-row; dotS/dotQ/rowsum/rowsumsq are
// kept as per-lane register partials and folded with the mask AFTER the
// barrier, then reduced once block-wide (6 values).
// seg==0 blocks additionally compute the source-row dots ss,qq once per
// (b,c) and store them in bpart slots 6,7 — removing the per-block
// recompute from s2f.
// Emits: 64-bit row mask + 6 masked block partials (+2 source dots on seg0)
// ---------------------------------------------------------------------------
__global__ __launch_bounds__(256) void s1(
    const float* __restrict__ h, const float* __restrict__ op,
    const float* __restrict__ opS, const float* __restrict__ opQ,
    unsigned long long* __restrict__ maskbuf, float* __restrict__ bpart) {
  const int blk = blockIdx.x;
  const int bc = blk >> 2, seg = blk & 3;
  const int c = bc & (Cc - 1);
  const float* __restrict__ tile = h + (size_t)bc * TILE;
  const int tid = threadIdx.x, lane = tid & 63, wv = tid >> 6;
  const int hw = tid >> 5, hl = tid & 31;

  __shared__ float s_dh[ROWS];
  __shared__ float s_red[4][6];
  __shared__ float s_cs;
  __shared__ float s_ssq[2];

  // wave 0: const_src = <source_row, op[c][0:FD]> -> LDS for all waves.
  // seg==0 blocks also produce the source-row dots for opS/opQ (slots 6,7).
  if (wv == 0) {
    const float* __restrict__ opc = op + c * 2 * FD;
    const float a = tile[lane], b = tile[lane + 64];
    float cs = a * opc[lane] + b * opc[lane + 64];
    float ssv = 0.0f, qqv = 0.0f;
    if (seg == 0) {
      const float* __restrict__ opSc = opS + c * 2 * FD + FD;
      const float* __restrict__ opQc = opQ + c * 2 * FD + FD;
      ssv = a * opSc[lane] + b * opSc[lane + 64];
      qqv = a * opQc[lane] + b * opQc[lane + 64];
    }
#pragma unroll
    for (int off = 32; off >= 1; off >>= 1) {
      cs  += __shfl_xor(cs,  off, 64);
      ssv += __shfl_xor(ssv, off, 64);
      qqv += __shfl_xor(qqv, off, 64);
    }
    if (lane == 0) { s_cs = cs; s_ssq[0] = ssv; s_ssq[1] = qqv; }
  }

  const float4 oH = ((const float4*)(op  + c * 2 * FD + FD))[hl];
  const float4 oS = ((const float4*)(opS + c * 2 * FD))[hl];
  const float4 oQ = ((const float4*)(opQ + c * 2 * FD))[hl];

  float dsp[8], dqp[8], rsp[8], rssp[8];

  // 8 half-waves x 8 rows = 64 rows; one float4 per half-wave-lane per row.
  // Per iteration only dh is butterfly-reduced (5 steps, both halves).
#pragma unroll
  for (int i = 0; i < 8; ++i) {
    const int nl = hw * 8 + i;
    const float4 v = ((const float4*)(tile + (size_t)(seg * ROWS + nl) * FD))[hl];
    float dh = v.x * oH.x + v.y * oH.y + v.z * oH.z + v.w * oH.w;
    dsp[i]  = v.x * oS.x + v.y * oS.y + v.z * oS.z + v.w * oS.w;
    dqp[i]  = v.x * oQ.x + v.y * oQ.y + v.z * oQ.z + v.w * oQ.w;
    rsp[i]  = v.x + v.y + v.z + v.w;
    rssp[i] = v.x * v.x + v.y * v.y + v.z * v.z + v.w * v.w;
#pragma unroll
    for (int off = 16; off >= 1; off >>= 1) dh += __shfl_xor(dh, off, 64);
    if (hl == 0) s_dh[nl] = dh;
  }
  __syncthreads();

  const float cs = s_cs;

  // ballot mask (wave 0 handles all 64 rows)
  if (wv == 0) {
    const bool m = (s_dh[lane] + cs) >= 0.0f;
    const unsigned long long bits = __ballot(m);
    if (lane == 0) maskbuf[blk] = bits;
  }

  // mask-weighted lane-local accumulation over this lane's 8 rows
  float a_ds = 0, a_dq = 0, a_rsm = 0, a_rsq = 0, a_rssm = 0, a_rssq = 0;
#pragma unroll
  for (int i = 0; i < 8; ++i) {
    const bool m = (s_dh[hw * 8 + i] + cs) >= 0.0f;
    a_ds   += m ? dsp[i]  : 0.0f;
    a_dq   += m ? 0.0f    : dqp[i];
    a_rsm  += m ? rsp[i]  : 0.0f;
    a_rsq  += m ? 0.0f    : rsp[i];
    a_rssm += m ? rssp[i] : 0.0f;
    a_rssq += m ? 0.0f    : rssp[i];
  }
  // one full-wave butterfly (6 steps x 6 values)
#pragma unroll
  for (int off = 32; off >= 1; off >>= 1) {
    a_ds   += __shfl_xor(a_ds,   off, 64);
    a_dq   += __shfl_xor(a_dq,   off, 64);
    a_rsm  += __shfl_xor(a_rsm,  off, 64);
    a_rsq  += __shfl_xor(a_rsq,  off, 64);
    a_rssm += __shfl_xor(a_rssm, off, 64);
    a_rssq += __shfl_xor(a_rssq, off, 64);
  }
  if (lane == 0) {
    s_red[wv][0] = a_ds;  s_red[wv][1] = a_dq;
    s_red[wv][2] = a_rsm; s_red[wv][3] = a_rsq;
    s_red[wv][4] = a_rssm; s_red[wv][5] = a_rssq;
  }
  __syncthreads();
  if (tid < 6) {
    bpart[(size_t)blk * 8 + tid] =
        s_red[0][tid] + s_red[1][tid] + s_red[2][tid] + s_red[3][tid];
  }
  if (seg == 0 && tid >= 6 && tid < 8) {
    bpart[(size_t)blk * 8 + tid] = s_ssq[tid - 6];
  }
}

// ---------------------------------------------------------------------------
// s2f: fused finalize + elementwise. One block per (bc, seg).
// Preamble now reads everything from bpart (8 slots: 6 seg-summed partials +
// 2 source dots from seg0) — no h gather, no operand loads, no long shuffle
// chains. Then per-b softmax weights + channel BN scale/shift, and
// elu(fma(h, w*scale, shift)) over the 32 KB slice (L3-hot re-read),
// nontemporal stores for the write-once output.
// ---------------------------------------------------------------------------
__global__ __launch_bounds__(256) void s2f(
    const float* __restrict__ h, const unsigned long long* __restrict__ maskbuf,
    const float* __restrict__ bpart, const float* __restrict__ gamma,
    const float* __restrict__ beta, float* __restrict__ out) {
  const int blk = blockIdx.x, bc = blk >> 2, seg = blk & 3;
  const int c = bc & (Cc - 1), bmine = bc >> 6;
  const int tid = threadIdx.x, lane = tid & 63, hw = tid >> 5, hl = tid & 31;
  __shared__ float s_S[Bb], s_SS[Bb], s_ws[2 * Bb];
  __shared__ float s_a[ROWS];

  const int b = hw;                    // 8 half-waves -> 8 batch entries
  const int bcb = b * Cc + c;

  // combine the 4 seg-partials (lanes hl<6, one j each); hl==6,7 read the
  // seg0-only source dots.
  float aj = 0.0f;
  if (hl < 6) {
#pragma unroll
    for (int k = 0; k < SEGS; ++k)
      aj += bpart[(size_t)(bcb * SEGS + k) * 8 + hl];
  } else if (hl < 8) {
    aj = bpart[(size_t)(bcb * SEGS) * 8 + hl];
  }
  const int base = lane & 32;
  float a0 = __shfl(aj, base + 0, 64), a1 = __shfl(aj, base + 1, 64);
  float a2 = __shfl(aj, base + 2, 64), a3 = __shfl(aj, base + 3, 64);
  float a4 = __shfl(aj, base + 4, 64), a5 = __shfl(aj, base + 5, 64);
  float ss = __shfl(aj, base + 6, 64), qq = __shfl(aj, base + 7, 64);

  float sa = a0 * (1.0f / Nn) + ss;
  float qa = a1 * (1.0f / Nn) + qq;
  float mx = fmaxf(sa, qa);
  float es = __expf(sa - mx), eq = __expf(qa - mx);
  float inv = 1.0f / (es + eq);
  float w_s = es * inv, w_q = eq * inv;
  if (hl == 0) {
    s_S[b]  = w_s * a2 + w_q * a3;
    s_SS[b] = w_s * w_s * a4 + w_q * w_q * a5;
    s_ws[2 * b] = w_s; s_ws[2 * b + 1] = w_q;
  }
  __syncthreads();

  // channel stats (all threads redundantly, LDS broadcast reads)
  float S = 0.0f, SS = 0.0f;
#pragma unroll
  for (int k = 0; k < Bb; ++k) { S += s_S[k]; SS += s_SS[k]; }
  const float invcnt = 1.0f / (float)(Bb * Nn * FD);
  const float mean = S * invcnt;
  const float var  = SS * invcnt - mean * mean;
  const float scale = gamma[c] * rsqrtf(var + 1e-5f);
  const float shift = beta[c] - mean * scale;

  if (tid < ROWS) {
    const unsigned long long m = maskbuf[blk];
    const float w = ((m >> tid) & 1ull) ? s_ws[2 * bmine] : s_ws[2 * bmine + 1];
    s_a[tid] = w * scale;
  }
  __syncthreads();

  const float4* __restrict__ h4 = (const float4*)(h + (size_t)bc * TILE) + seg * 2048;
  floatx4* __restrict__ o4 = (floatx4*)(out + (size_t)bc * TILE) + seg * 2048;
#pragma unroll
  for (int k = 0; k < 8; ++k) {
    const int idx = k * 256 + tid;
    const float a = s_a[idx >> 5];   // 32 float4 per row -> broadcast per 32 lanes
    float4 v = h4[idx];
    floatx4 r;
    r.x = fmaf(v.x, a, shift);
    r.y = fmaf(v.y, a, shift);
    r.z = fmaf(v.z, a, shift);
    r.w = fmaf(v.w, a, shift);
    r.x = r.x > 0.0f ? r.x : __expf(r.x) - 1.0f;
    r.y = r.y > 0.0f ? r.y : __expf(r.y) - 1.0f;
    r.z = r.z > 0.0f ? r.z : __expf(r.z) - 1.0f;
    r.w = r.w > 0.0f ? r.w : __expf(r.w) - 1.0f;
    __builtin_nontemporal_store(r, &o4[idx]);
  }
}

extern "C" void kernel_launch(void* const* d_in, const int* in_sizes, int n_in,
                              void* d_out, int out_size, void* d_ws, size_t ws_size,
                              hipStream_t stream) {
  const float* h     = (const float*)d_in[0];
  const float* op    = (const float*)d_in[1];
  const float* opS   = (const float*)d_in[2];
  const float* opQ   = (const float*)d_in[3];
  const float* gamma = (const float*)d_in[4];
  const float* beta  = (const float*)d_in[5];
  float* out = (float*)d_out;

  unsigned long long* maskbuf = (unsigned long long*)d_ws;   // 2048 u64 = 16 KB
  float* bpart = (float*)((char*)d_ws + 16384);              // 2048*8 floats = 64 KB

  s1<<<Bb * Cc * SEGS, 256, 0, stream>>>(h, op, opS, opQ, maskbuf, bpart);
  s2f<<<Bb * Cc * SEGS, 256, 0, stream>>>(h, maskbuf, bpart, gamma, beta, out);
}